// Round 5
// baseline (109.752 us; speedup 1.0000x reference)
//
#include <hip/hip_runtime.h>

// FusedSOSCascade as truncated-FIR via MFMA (fp16 split precision).
// y[T] = sum_{j=0}^{287} h[j] x[T-j]  (h = cascade impulse response;
// poles r<0.95 -> tail beyond 288 taps < 1e-6 -- far below fp32 noise).
//
// Kernel A (1 block): h[0..287] by 8-lane systolic DF2T cascade (exact fp32
//   recurrence), then per-lane-swizzled B fragments (fp16 hi/lo split) to ws.
// Kernel B (8192 x 64): per wave, one 32x32 MFMA tile = 1024 consecutive
//   outputs of one channel. A[m][k] = x[T0 + 32m + k - 256] staged in LDS as
//   fp16 hi/lo; B[k][n] = h[n + 256 - k]. 18 K-steps of 16, 3 products/step
//   (xh*hh + xh*hl + xl*hh) accumulate fp32. Method error ~2^-22 relative.
// Fragment maps (gfx950 v_mfma_f32_32x32x16_f16):
//   A[m][k]: m = lane&31, k = 8*(lane>>5)+b       (b in [0,8))
//   B[k][n]: n = lane&31, k = 8*(lane>>5)+b
//   D[row][col]: col = lane&31, row = (r&3)+8*(r>>2)+4*(lane>>5)  [m74/m101]

typedef _Float16 half8 __attribute__((ext_vector_type(8)));
typedef _Float16 half4 __attribute__((ext_vector_type(4)));
typedef float f32x16 __attribute__((ext_vector_type(16)));
typedef unsigned short ushort8 __attribute__((ext_vector_type(8)));

#define T_LEN   65536
#define TAPS    288
#define KSTEPS  18                 // 288 / 16
#define TILE    1024               // outputs per wave (one 32x32 tile span)
#define REG     1280               // staged floats: TILE + 256 halo
#define PADU(u) ((u) + (((u) >> 6) << 3))   // +8 halfs per 64 (bank spread)
#define LDSH    (REG + (REG >> 6) * 8)      // 1440 halfs per array

// ---------------- Kernel A: impulse response + swizzled B fragments --------
__global__ __launch_bounds__(256)
void sos_prep_kernel(const float* __restrict__ sos,
                     unsigned short* __restrict__ ws) {
  __shared__ float hsh[TAPS];
  const int tid = threadIdx.x;

  if (tid < 64) {
    // lanes 0..7 = sections 0..7; other lanes carry zeros (harmless).
    float cb0 = 0.f, cb1 = 0.f, cb2 = 0.f, ca1 = 0.f, ca2 = 0.f;
    if (tid < 8) {
      const float a0 = sos[tid * 6 + 3];
      cb0 = sos[tid * 6 + 0] / a0;
      cb1 = sos[tid * 6 + 1] / a0;
      cb2 = sos[tid * 6 + 2] / a0;
      ca1 = -(sos[tid * 6 + 4] / a0);
      ca2 = -(sos[tid * 6 + 5] / a0);
    }
    // Systolic: at wall-step tau, lane k processes sample (tau - k) of its
    // section, input = lane k-1's output from the previous wall-step.
    float z1 = 0.f, z2 = 0.f, yprev = 0.f;
    for (int tau = 0; tau < TAPS + 7; ++tau) {
      float in = __shfl_up(yprev, 1);
      if (tid == 0) in = (tau == 0) ? 1.f : 0.f;   // impulse
      float y = fmaf(cb0, in, z1);
      z1 = fmaf(cb1, in, fmaf(ca1, y, z2));
      z2 = fmaf(cb2, in, ca2 * y);
      yprev = y;
      if (tid == 7 && tau >= 7) hsh[tau - 7] = y;  // h[tau-7]
    }
  }
  __syncthreads();

  // B fragments, pre-swizzled per consuming lane: item = st*64 + lane.
  for (int it = tid; it < KSTEPS * 64; it += 256) {
    const int st = it >> 6, l = it & 63;
    ushort8 hv, lv;
#pragma unroll
    for (int b = 0; b < 8; ++b) {
      const int j = (l & 31) + 256 - 16 * st - 8 * (l >> 5) - b;
      const float v = (j >= 0 && j < TAPS) ? hsh[j] : 0.f;
      const _Float16 vh = (_Float16)v;
      const _Float16 vl = (_Float16)(v - (float)vh);
      hv[b] = __builtin_bit_cast(unsigned short, vh);
      lv[b] = __builtin_bit_cast(unsigned short, vl);
    }
    ((uint4*)ws)[it]               = __builtin_bit_cast(uint4, hv);
    ((uint4*)ws)[KSTEPS * 64 + it] = __builtin_bit_cast(uint4, lv);
  }
}

// ---------------- Kernel B: implicit-GEMM FIR ------------------------------
__global__ __launch_bounds__(64, 2)
void FusedSOSCascade_20040317403806_kernel(const float* __restrict__ x,
                                           const unsigned short* __restrict__ ws,
                                           float* __restrict__ out) {
  __shared__ _Float16 xhi[LDSH];
  __shared__ _Float16 xlo[LDSH];

  const int l  = threadIdx.x;            // 0..63
  const int w  = blockIdx.x;             // 0..8191
  const int c  = w >> 6;                 // 64 tiles per channel
  const int T0 = (w & 63) << 10;         // tile base time
  const float* xc = x + (size_t)c * T_LEN;

  // ---- Stage x[T0-256, T0+1024) as fp16 hi/lo split (zeros below 0).
  {
    float4 v[5];
#pragma unroll
    for (int ro = 0; ro < 5; ++ro) {
      const int u = (ro * 64 + l) << 2;         // 0..1276, mult of 4
      const int g = T0 - 256 + u;
      float4 t = make_float4(0.f, 0.f, 0.f, 0.f);
      if (g >= 0) t = *(const float4*)(xc + g); // g%4==0, in-bounds high side
      v[ro] = t;
    }
#pragma unroll
    for (int ro = 0; ro < 5; ++ro) {
      const int u = (ro * 64 + l) << 2;
      const int p = PADU(u);                    // 8B-aligned, pad-safe
      half4 h4, l4;
      h4.x = (_Float16)v[ro].x;  l4.x = (_Float16)(v[ro].x - (float)h4.x);
      h4.y = (_Float16)v[ro].y;  l4.y = (_Float16)(v[ro].y - (float)h4.y);
      h4.z = (_Float16)v[ro].z;  l4.z = (_Float16)(v[ro].z - (float)h4.z);
      h4.w = (_Float16)v[ro].w;  l4.w = (_Float16)(v[ro].w - (float)h4.w);
      *(half4*)&xhi[p] = h4;
      *(half4*)&xlo[p] = l4;
    }
  }
  __syncthreads();

  // ---- B fragments (hi+lo) from ws: coalesced dwordx4, L2-resident.
  half8 bh[KSTEPS], bl[KSTEPS];
  const uint4* B = (const uint4*)ws;
#pragma unroll
  for (int st = 0; st < KSTEPS; ++st) {
    bh[st] = __builtin_bit_cast(half8, B[st * 64 + l]);
    bl[st] = __builtin_bit_cast(half8, B[KSTEPS * 64 + st * 64 + l]);
  }

  // ---- 18 K-steps x 3 MFMA, fp32 accumulate.
  f32x16 acc = {};
  const int abase = 32 * (l & 31) + 8 * (l >> 5);
#pragma unroll
  for (int st = 0; st < KSTEPS; ++st) {
    const int u = abase + 16 * st;              // mult of 8, pad-safe
    const int p = PADU(u);                      // 16B-aligned -> ds_read_b128
    const half8 ah = *(const half8*)&xhi[p];
    const half8 al = *(const half8*)&xlo[p];
    acc = __builtin_amdgcn_mfma_f32_32x32x16_f16(ah, bh[st], acc, 0, 0, 0);
    acc = __builtin_amdgcn_mfma_f32_32x32x16_f16(ah, bl[st], acc, 0, 0, 0);
    acc = __builtin_amdgcn_mfma_f32_32x32x16_f16(al, bh[st], acc, 0, 0, 0);
  }

  // ---- Store: D[row][col] -> y[T0 + 32*row + col].
  float* oc = out + (size_t)c * T_LEN + T0;
#pragma unroll
  for (int r = 0; r < 16; ++r) {
    const int row = (r & 3) + 8 * (r >> 2) + 4 * (l >> 5);
    oc[(row << 5) + (l & 31)] = acc[r];
  }
}

extern "C" void kernel_launch(void* const* d_in, const int* in_sizes, int n_in,
                              void* d_out, int out_size, void* d_ws, size_t ws_size,
                              hipStream_t stream) {
  const float* x   = (const float*)d_in[0];   // [128, 65536] fp32
  const float* sos = (const float*)d_in[1];   // [8, 6] fp32
  float* out = (float*)d_out;                 // [128, 65536] fp32
  (void)in_sizes; (void)n_in; (void)out_size; (void)ws_size;

  unsigned short* B = (unsigned short*)d_ws;  // 36,864 B used

  sos_prep_kernel<<<dim3(1), dim3(256), 0, stream>>>(sos, B);
  FusedSOSCascade_20040317403806_kernel<<<dim3(8192), dim3(64), 0, stream>>>(
      x, B, out);
}